// Round 15
// baseline (606.927 us; speedup 1.0000x reference)
//
#include <hip/hip_runtime.h>

#define NN 30000   // nodes
#define MMN 16     // neighbors
#define NF 1024    // input features
#define NC 16      // classes
#define KC 8       // capsules
#define DDIM 32    // dims per capsule
#define DR 256     // rep dim

typedef __bf16 bf16x8 __attribute__((ext_vector_type(8)));
typedef __bf16 bf16x4 __attribute__((ext_vector_type(4)));
typedef float floatx4 __attribute__((ext_vector_type(4)));

__device__ inline void splitbf(float v, __bf16& h, __bf16& l) {
  h = (__bf16)v;                 // RNE
  l = (__bf16)(v - (float)h);    // residual
}

// ---- DPP cross-lane helpers ----
template <int C>
__device__ __forceinline__ float dppadd(float x) {
  return x + __int_as_float(
      __builtin_amdgcn_update_dpp(0, __float_as_int(x), C, 0xF, 0xF, true));
}
template <int C>
__device__ __forceinline__ float dppmov(float x) {
  return __int_as_float(
      __builtin_amdgcn_update_dpp(0, __float_as_int(x), C, 0xF, 0xF, true));
}
// sum + broadcast over an aligned 8-lane group (capsule dims)
__device__ __forceinline__ float red8(float x) {
  x = dppadd<0xB1>(x);   // quad_perm xor1
  x = dppadd<0x4E>(x);   // quad_perm xor2
  x = dppadd<0x141>(x);  // row_half_mirror crosses quads within 8 (quads uniform by now)
  return x;
}
// sum + broadcast across the 8 capsule groups (lane stride 8)
__device__ __forceinline__ float redk(float x) {
  x = dppadd<0x128>(x);  // xor8 via row_ror:8
  x = x + __int_as_float(__builtin_amdgcn_ds_swizzle(__float_as_int(x), 0x401F));  // xor16
  x = x + __shfl_xor(x, 32);                                                       // xor32
  return x;
}
// sum + broadcast over an aligned 16-lane group (mlp classes)
__device__ __forceinline__ float red16sum(float x) {
  x = dppadd<0xB1>(x);
  x = dppadd<0x4E>(x);
  x = x + __int_as_float(__builtin_amdgcn_ds_swizzle(__float_as_int(x), 0x101F));  // xor4
  x = x + __int_as_float(__builtin_amdgcn_ds_swizzle(__float_as_int(x), 0x201F));  // xor8
  return x;
}
__device__ __forceinline__ float red16max(float x) {
  x = fmaxf(x, dppmov<0xB1>(x));
  x = fmaxf(x, dppmov<0x4E>(x));
  x = fmaxf(x, __int_as_float(__builtin_amdgcn_ds_swizzle(__float_as_int(x), 0x101F)));
  x = fmaxf(x, __int_as_float(__builtin_amdgcn_ds_swizzle(__float_as_int(x), 0x201F)));
  return x;
}

// ---- reduce-scatter over an 8-lane group (routing distributed softmax) ----
__device__ __forceinline__ float rscatter8(const float p[8], int lane) {
  const bool j4 = (lane & 4) != 0, j2 = (lane & 2) != 0, j1 = (lane & 1) != 0;
  float k0 = j4 ? p[4] : p[0];
  float k1 = j4 ? p[5] : p[1];
  float k2 = j4 ? p[6] : p[2];
  float k3 = j4 ? p[7] : p[3];
  float s0 = j4 ? p[0] : p[4];
  float s1 = j4 ? p[1] : p[5];
  float s2 = j4 ? p[2] : p[6];
  float s3 = j4 ? p[3] : p[7];
  k0 += dppmov<0x141>(s0); k1 += dppmov<0x141>(s1);
  k2 += dppmov<0x141>(s2); k3 += dppmov<0x141>(s3);
  float t0 = j2 ? k2 : k0;
  float t1 = j2 ? k3 : k1;
  float u0 = j2 ? k0 : k2;
  float u1 = j2 ? k1 : k3;
  t0 += dppmov<0x4E>(u0); t1 += dppmov<0x4E>(u1);
  float a = j1 ? t1 : t0;
  float b = j1 ? t0 : t1;
  a += dppmov<0xB1>(b);
  return a;   // d for m = (lane&7)
}

// ---- allgather over an 8-lane group ----
__device__ __forceinline__ void agather8(float a, float w[8], int lane) {
  const bool j4 = (lane & 4) != 0, j2 = (lane & 2) != 0, j1 = (lane & 1) != 0;
  float pa = dppmov<0xB1>(a);
  float b0 = j1 ? pa : a;
  float b1 = j1 ? a : pa;
  float p0 = dppmov<0x4E>(b0), p1 = dppmov<0x4E>(b1);
  float q0 = j2 ? p0 : b0;
  float q1 = j2 ? p1 : b1;
  float q2 = j2 ? b0 : p0;
  float q3 = j2 ? b1 : p1;
  float m0 = dppmov<0x141>(q0), m1 = dppmov<0x141>(q1);
  float m2 = dppmov<0x141>(q2), m3 = dppmov<0x141>(q3);
  w[0] = j4 ? m0 : q0;  w[1] = j4 ? m1 : q1;
  w[2] = j4 ? m2 : q2;  w[3] = j4 ? m3 : q3;
  w[4] = j4 ? q0 : m0;  w[5] = j4 ? q1 : m1;
  w[6] = j4 ? q2 : m2;  w[7] = j4 ? q3 : m3;
}

// ---------------- wt_build: w [1024,256] -> FRAGMENT-LINEAR bf16 hi/lo ----------------
__global__ __launch_bounds__(256) void wt_build_kernel(
    const float* __restrict__ w, __bf16* __restrict__ wt_hi, __bf16* __restrict__ wt_lo) {
  const int gid  = blockIdx.x * 256 + threadIdx.x;  // 32768 = 32 kc x 16 g x 64 lanes
  const int lane = gid & 63;
  const int kc   = gid >> 10;
  const int g    = (gid >> 6) & 15;
  const int c = g * 16 + (lane & 15);
  const int k = kc * 32 + (lane >> 4) * 8;
  bf16x8 h, l;
#pragma unroll
  for (int j = 0; j < 8; ++j) {
    const float v = w[(size_t)(k + j) * DR + c];
    __bf16 hh, ll; splitbf(v, hh, ll);
    h[j] = hh; l[j] = ll;
  }
  *(bf16x8*)(wt_hi + (size_t)gid * 8) = h;
  *(bf16x8*)(wt_lo + (size_t)gid * 8) = l;
}

// ---------------- pad_zero ----------------
__global__ void pad_zero_kernel(float* __restrict__ p) {
  ((float4*)p)[threadIdx.x] = make_float4(0.f, 0.f, 0.f, 0.f);  // 64 threads x 16B
}

// ---------------- PCA via split-bf16 MFMA: P = relu(x @ w + b) ----------------
// r14: XCD swizzle cut FETCH 242->66MB but only -5% time -> not BW-bound; limiter is
// thin TLP (3.75 blocks/CU) + 8-way LDS write conflicts ([128][40]: 80B=20banks,
// gcd(20,32)=4). This round: 64x64 tiles -> 1888 blocks (7.4/CU, launch_bounds(256,8),
// acc[4] ~40 VGPR fits 64-cap) + LDS stride 42 (84B=21banks, gcd 1 -> full spread).
// r6's 64-tile failure was confounded by scattered-wt (pre-r7); fragment-linear wt
// (1 segment/inst) removes that. XCD-sibling swizzle retained.
__global__ __launch_bounds__(256, 8) void pca_mfma_kernel(
    const float* __restrict__ x, const __bf16* __restrict__ wt_hi,
    const __bf16* __restrict__ wt_lo, const float* __restrict__ b,
    float* __restrict__ out) {
  __shared__ __bf16 Ah[64][42];
  __shared__ __bf16 Al[64][42];
  const int t    = threadIdx.x;
  const int lane = t & 63;
  const int wv   = t >> 6;        // wave owns rows wv*16..wv*16+15
  const int q    = lane >> 4;
  const int lm   = lane & 15;
  // swizzled decode: all 4 col-group siblings of a row-block share bid%8 -> same XCD
  const int bid  = blockIdx.x;                      // grid 1888 = 8 * 236
  const int slot = bid >> 3;                        // 0..235
  const int cg   = (slot & 3) << 2;                 // col-group base (16-col units)
  const int rblk = ((slot >> 2) << 3) + (bid & 7);  // row-block 0..471
  const int rowBase = rblk << 6;
  const int colBase = cg << 4;

  const int sr = t >> 2;          // staging row 0..63
  const int sc = (t & 3) << 3;    // staging col 0,8,16,24 (floats)

  floatx4 acc[4];
#pragma unroll
  for (int ct = 0; ct < 4; ++ct) acc[ct] = (floatx4){0.f, 0.f, 0.f, 0.f};

  const float* xr = x + (size_t)(rowBase + sr) * NF + sc;
  const bool ok = (rowBase + sr) < NN;

  const __bf16* wfh = wt_hi + ((size_t)cg << 9) + (lane << 3);
  const __bf16* wfl = wt_lo + ((size_t)cg << 9) + (lane << 3);

  float4 xv[2];
  xv[0] = ok ? *(const float4*)(xr)     : make_float4(0.f, 0.f, 0.f, 0.f);
  xv[1] = ok ? *(const float4*)(xr + 4) : make_float4(0.f, 0.f, 0.f, 0.f);

  for (int k0 = 0; k0 < NF; k0 += 32) {
    const int kc = k0 >> 5;
    bf16x8 bh[4], bl[4];
#pragma unroll
    for (int ct = 0; ct < 4; ++ct) {
      bh[ct] = *(const bf16x8*)(wfh + (((size_t)kc << 4) + ct) * 512);
      bl[ct] = *(const bf16x8*)(wfl + (((size_t)kc << 4) + ct) * 512);
    }
    // barrier 1: prior chunk's ds_reads done before LDS overwrite (no vmcnt drain)
    asm volatile("s_waitcnt lgkmcnt(0)" ::: "memory");
    __builtin_amdgcn_s_barrier();
    {
      bf16x8 h8, l8;
      const float vs[8] = {xv[0].x, xv[0].y, xv[0].z, xv[0].w,
                           xv[1].x, xv[1].y, xv[1].z, xv[1].w};
#pragma unroll
      for (int j = 0; j < 8; ++j) { __bf16 H, L; splitbf(vs[j], H, L); h8[j] = H; l8[j] = L; }
      *(bf16x8*)&Ah[sr][sc] = h8;
      *(bf16x8*)&Al[sr][sc] = l8;
    }
    // prefetch next chunk's x — stays in flight across the barrier
    float4 xn[2];
    if (k0 + 32 < NF && ok) {
      xn[0] = *(const float4*)(xr + k0 + 32);
      xn[1] = *(const float4*)(xr + k0 + 36);
    } else {
      xn[0] = make_float4(0.f, 0.f, 0.f, 0.f);
      xn[1] = make_float4(0.f, 0.f, 0.f, 0.f);
    }
    // barrier 2: all waves' ds_writes visible before fragment reads (no vmcnt drain)
    asm volatile("s_waitcnt lgkmcnt(0)" ::: "memory");
    __builtin_amdgcn_s_barrier();
    const int ar = (wv << 4) + lm;
    const bf16x8 ah = *(const bf16x8*)&Ah[ar][q << 3];
    const bf16x8 al = *(const bf16x8*)&Al[ar][q << 3];
#pragma unroll
    for (int ct = 0; ct < 4; ++ct) {
      acc[ct] = __builtin_amdgcn_mfma_f32_16x16x32_bf16(ah, bh[ct], acc[ct], 0, 0, 0);
      acc[ct] = __builtin_amdgcn_mfma_f32_16x16x32_bf16(ah, bl[ct], acc[ct], 0, 0, 0);
      acc[ct] = __builtin_amdgcn_mfma_f32_16x16x32_bf16(al, bh[ct], acc[ct], 0, 0, 0);
    }
    xv[0] = xn[0];
    xv[1] = xn[1];
  }
  // epilogue: bias + relu; C/D layout col=lane&15, row=quad*4+reg
#pragma unroll
  for (int ct = 0; ct < 4; ++ct) {
    const int col = colBase + (ct << 4) + lm;
    const float bias = b[col];
#pragma unroll
    for (int r = 0; r < 4; ++r) {
      const int row = rowBase + (wv << 4) + (q << 2) + r;
      if (row < NN) out[(size_t)row * DR + col] = fmaxf(acc[ct][r] + bias, 0.f);
    }
  }
}

// ---------- layer-0 normalize (k wave-uniform via blockIdx.y; round-8 form) ----------
__global__ __launch_bounds__(256, 4) void norm_fc_kernel(
    const float* __restrict__ hin, const float* __restrict__ fcw,
    const float* __restrict__ fcb, float* __restrict__ q) {
  const int k = blockIdx.y;
  const int n = blockIdx.x * 256 + threadIdx.x;
  if (n > NN) return;
  float* qrow = q + (size_t)n * DR + k * DDIM;
  if (n == NN) {
#pragma unroll
    for (int i = 0; i < DDIM; i += 4)
      *(float4*)(qrow + i) = make_float4(0.f, 0.f, 0.f, 0.f);
    return;
  }
  const float* hrow = hin + (size_t)n * DR + k * DDIM;
  float v[DDIM];
  float ss = 0.f;
#pragma unroll
  for (int i = 0; i < DDIM; i += 4) {
    float4 tv = *(const float4*)(hrow + i);
    tv.x = fmaxf(tv.x, 0.f); tv.y = fmaxf(tv.y, 0.f);
    tv.z = fmaxf(tv.z, 0.f); tv.w = fmaxf(tv.w, 0.f);
    v[i] = tv.x; v[i+1] = tv.y; v[i+2] = tv.z; v[i+3] = tv.w;
    ss += tv.x*tv.x + tv.y*tv.y + tv.z*tv.z + tv.w*tv.w;
  }
  float inv = 1.f / fmaxf(sqrtf(ss), 1e-12f);
#pragma unroll
  for (int i = 0; i < DDIM; ++i) v[i] *= inv;
#pragma unroll
  for (int i = 0; i < DDIM; ++i) asm volatile("" : "+v"(v[i]));
  float y[DDIM];
  ss = 0.f;
  const float* wk = fcw + (size_t)k * DDIM * DDIM;   // wave-uniform -> s_load
  const float* bk = fcb + k * DDIM;
#pragma unroll 4
  for (int o = 0; o < DDIM; ++o) {
    float a = bk[o];
#pragma unroll
    for (int i = 0; i < DDIM; i += 4) {
      const float4 wv = *(const float4*)(wk + o * DDIM + i);
      a += v[i]*wv.x + v[i+1]*wv.y + v[i+2]*wv.z + v[i+3]*wv.w;
    }
    a = fmaxf(a, 0.f);
    y[o] = a;
    ss += a * a;
  }
  inv = 1.f / fmaxf(sqrtf(ss), 1e-12f);
#pragma unroll
  for (int o = 0; o < DDIM; o += 4) {
    float4 tv;
    tv.x = y[o]*inv; tv.y = y[o+1]*inv; tv.z = y[o+2]*inv; tv.w = y[o+3]*inv;
    *(float4*)(qrow + o) = tv;
  }
}

// ---------------- routing: wave per node, DISTRIBUTED softmax (round-9 form) ----------------
__global__ __launch_bounds__(256, 4) void routing_kernel(
    const float* __restrict__ tab, const float* __restrict__ padrow,
    const int* __restrict__ nbr, const float* __restrict__ rawp,
    const int* __restrict__ ritp, float* __restrict__ uout, const int doNorm) {
  const int lane = threadIdx.x & 63;
  const int node = blockIdx.x * 4 + (threadIdx.x >> 6);
  const int off = (lane >> 3) * DDIM + (lane & 7) * 4;  // group (lane>>3) = capsule
  const float param = 1.f / (1.f + __expf(-rawp[0]));
  const float qparam = 1.f - param;
  const int iters = ritp[0];

  float4 z[MMN];
#pragma unroll
  for (int m = 0; m < MMN; ++m) {
    const int j = nbr[node * MMN + m];                    // wave-uniform
    const float* zrow = (j == NN) ? padrow : (tab + (size_t)j * DR);
    z[m] = *(const float4*)(zrow + off);
  }
  float4 ub = *(const float4*)(tab + (size_t)node * DR + off);

  // ---- iteration 0 (p == 0): uniform routing weights ----
  float4 S = make_float4(0.f, 0.f, 0.f, 0.f);
#pragma unroll
  for (int m = 0; m < MMN; ++m) {
    S.x += z[m].x; S.y += z[m].y; S.z += z[m].z; S.w += z[m].w;
  }
  const float w0 = param * 0.0625f + qparam * 0.125f;  // param/16 + (1-param)/8
  ub.x += w0 * S.x; ub.y += w0 * S.y; ub.z += w0 * S.z; ub.w += w0 * S.w;

  float4 u = ub;
  if (iters > 1) {
    float ss = red8(ub.x*ub.x + ub.y*ub.y + ub.z*ub.z + ub.w*ub.w);
    const float inv = 1.f / fmaxf(sqrtf(ss), 1e-12f);
    u.x = ub.x*inv; u.y = ub.y*inv; u.z = ub.z*inv; u.w = ub.w*inv;
  }

  for (int it = 1; it < iters; ++it) {
    float pA[8], pB[8];
#pragma unroll
    for (int m = 0; m < 8; ++m) {
      pA[m] = z[m].x*u.x + z[m].y*u.y + z[m].z*u.z + z[m].w*u.w;
      pB[m] = z[m+8].x*u.x + z[m+8].y*u.y + z[m+8].z*u.z + z[m+8].w*u.w;
    }
    const float dA = rscatter8(pA, lane);
    const float dB = rscatter8(pB, lane);
    const float eA = __expf(dA);
    const float eB = __expf(dB);
    const float smk = red8(eA + eB);
    const float skA = redk(eA);
    const float skB = redk(eB);
    const float c1 = param * __builtin_amdgcn_rcpf(smk);
    const float wA = eA * (c1 + qparam * __builtin_amdgcn_rcpf(skA));
    const float wB = eB * (c1 + qparam * __builtin_amdgcn_rcpf(skB));
    float wS[8], wT[8];
    agather8(wA, wS, lane);
    agather8(wB, wT, lane);
    float4 un = ub;
#pragma unroll
    for (int m = 0; m < 8; ++m) {
      un.x += wS[m]*z[m].x;   un.y += wS[m]*z[m].y;
      un.z += wS[m]*z[m].z;   un.w += wS[m]*z[m].w;
      un.x += wT[m]*z[m+8].x; un.y += wT[m]*z[m+8].y;
      un.z += wT[m]*z[m+8].z; un.w += wT[m]*z[m+8].w;
    }
    ub = un;
    if (it < iters - 1) {
      float ss = red8(un.x*un.x + un.y*un.y + un.z*un.z + un.w*un.w);
      const float inv = 1.f / fmaxf(sqrtf(ss), 1e-12f);
      u.x = un.x*inv; u.y = un.y*inv; u.z = un.z*inv; u.w = un.w*inv;
    }
  }
  float4 w = ub;
  if (doNorm) {
    w.x = fmaxf(w.x, 0.f); w.y = fmaxf(w.y, 0.f);
    w.z = fmaxf(w.z, 0.f); w.w = fmaxf(w.w, 0.f);
    float ss = red8(w.x*w.x + w.y*w.y + w.z*w.z + w.w*w.w);
    const float inv = 1.f / fmaxf(sqrtf(ss), 1e-12f);
    w.x *= inv; w.y *= inv; w.z *= inv; w.w *= inv;
  }
  *(float4*)(uout + (size_t)node * DR + off) = w;
}

// ---------------- MLP head via split-bf16 MFMA + log_softmax (round-10 form) ----------------
__global__ __launch_bounds__(256) void mlp_kernel(
    const float* __restrict__ h, const float* __restrict__ w,
    const float* __restrict__ b, float* __restrict__ out) {
  const int lane = threadIdx.x & 63;
  const int wv   = threadIdx.x >> 6;
  const int q    = lane >> 4;
  const int lm   = lane & 15;
  const int nodeTile = blockIdx.x * 64 + wv * 16;
  const int nodeA = nodeTile + lm;            // A-operand row owned by this lane
  const bool okA = nodeA < NN;
  const float* hp = h + (size_t)nodeA * DR + (q << 3);
  const float* wp = w + (size_t)lm * DR + (q << 3);

  floatx4 acc = (floatx4){0.f, 0.f, 0.f, 0.f};
#pragma unroll
  for (int kc = 0; kc < 8; ++kc) {
    bf16x8 ah, al, bh, bl;
    {
      float va[8];
      if (okA) {
        *(float4*)&va[0] = *(const float4*)(hp + kc * 32);
        *(float4*)&va[4] = *(const float4*)(hp + kc * 32 + 4);
      } else {
#pragma unroll
        for (int j = 0; j < 8; ++j) va[j] = 0.f;
      }
#pragma unroll
      for (int j = 0; j < 8; ++j) { __bf16 H, L; splitbf(va[j], H, L); ah[j] = H; al[j] = L; }
    }
    {
      float vb[8];
      *(float4*)&vb[0] = *(const float4*)(wp + kc * 32);
      *(float4*)&vb[4] = *(const float4*)(wp + kc * 32 + 4);
#pragma unroll
      for (int j = 0; j < 8; ++j) { __bf16 H, L; splitbf(vb[j], H, L); bh[j] = H; bl[j] = L; }
    }
    acc = __builtin_amdgcn_mfma_f32_16x16x32_bf16(ah, bh, acc, 0, 0, 0);
    acc = __builtin_amdgcn_mfma_f32_16x16x32_bf16(ah, bl, acc, 0, 0, 0);
    acc = __builtin_amdgcn_mfma_f32_16x16x32_bf16(al, bh, acc, 0, 0, 0);
  }
  const float bias = b[lm];
#pragma unroll
  for (int r = 0; r < 4; ++r) {
    const int nrow = nodeTile + (q << 2) + r;
    const float lg = acc[r] + bias;
    const float mx = red16max(lg);
    const float e  = __expf(lg - mx);
    const float se = red16sum(e);
    const float lp = lg - mx - __logf(se);
    if (nrow < NN) out[(size_t)nrow * NC + lm] = lp;
  }
}

extern "C" void kernel_launch(void* const* d_in, const int* in_sizes, int n_in,
                              void* d_out, int out_size, void* d_ws, size_t ws_size,
                              hipStream_t stream) {
  const float* x     = (const float*)d_in[0];
  const int*   nbr   = (const int*)  d_in[1];
  const float* pca_w = (const float*)d_in[2];
  const float* pca_b = (const float*)d_in[3];
  const float* rawp  = (const float*)d_in[4];
  const float* fc_w  = (const float*)d_in[5];
  const float* fc_b  = (const float*)d_in[6];
  const float* mlp_w = (const float*)d_in[7];
  const float* mlp_b = (const float*)d_in[8];
  const int*   ritp  = (const int*)  d_in[9];

  float* out  = (float*)d_out;                  // log_probs [NN,NC] then h [NN,DR]
  float* EMB  = out + (size_t)NN * NC;          // embedding region; also ping table B rows
  float* Bpad = EMB - DR;                       // table-B zero row (dead until mlp)
  float* Q    = (float*)d_ws;                   // [NN+1, DR] table A (+pad row NN)
  float* Qpad = Q + (size_t)NN * DR;

  // wt scratch: first 1MB of log_probs region (disjoint from Bpad; dead until mlp)
  __bf16* wt_hi = (__bf16*)d_out;               // fragment-linear [32][16][64][8]
  __bf16* wt_lo = wt_hi + (size_t)DR * NF;

  wt_build_kernel<<<128, 256, 0, stream>>>(pca_w, wt_hi, wt_lo);
  pad_zero_kernel<<<1, 64, 0, stream>>>(Bpad);
  // PCA + relu -> raw h rows at EMB (64x64 tiles, XCD-sibling swizzle, 1888 blocks)
  pca_mfma_kernel<<<1888, 256, 0, stream>>>(x, wt_hi, wt_lo, pca_b, EMB);
  // layer 0 prep (per-capsule fc) -> Q ; k wave-uniform via blockIdx.y
  norm_fc_kernel<<<dim3((NN + 1 + 255) / 256, KC), 256, 0, stream>>>(EMB, fc_w, fc_b, Q);
  // L0: Q -> B (normalized epilogue)
  routing_kernel<<<NN / 4, 256, 0, stream>>>(Q, Qpad, nbr, rawp, ritp, EMB, 1);
  // L1: B -> Q (normalized epilogue)
  routing_kernel<<<NN / 4, 256, 0, stream>>>(EMB, Bpad, nbr, rawp, ritp, Q, 1);
  // L2: Q -> EMB raw (final embedding)
  routing_kernel<<<NN / 4, 256, 0, stream>>>(Q, Qpad, nbr, rawp, ritp, EMB, 0);
  // classifier head (16-node x 16-class MFMA tiles)
  mlp_kernel<<<(NN + 63) / 64, 256, 0, stream>>>(EMB, mlp_w, mlp_b, out);
}

// Round 16
// 526.808 us; speedup vs baseline: 1.1521x; 1.1521x over previous
//
#include <hip/hip_runtime.h>

#define NN 30000   // nodes
#define MMN 16     // neighbors
#define NF 1024    // input features
#define NC 16      // classes
#define KC 8       // capsules
#define DDIM 32    // dims per capsule
#define DR 256     // rep dim

typedef __bf16 bf16x8 __attribute__((ext_vector_type(8)));
typedef __bf16 bf16x4 __attribute__((ext_vector_type(4)));
typedef float floatx4 __attribute__((ext_vector_type(4)));

__device__ inline void splitbf(float v, __bf16& h, __bf16& l) {
  h = (__bf16)v;                 // RNE
  l = (__bf16)(v - (float)h);    // residual
}

// ---- DPP cross-lane helpers ----
template <int C>
__device__ __forceinline__ float dppadd(float x) {
  return x + __int_as_float(
      __builtin_amdgcn_update_dpp(0, __float_as_int(x), C, 0xF, 0xF, true));
}
template <int C>
__device__ __forceinline__ float dppmov(float x) {
  return __int_as_float(
      __builtin_amdgcn_update_dpp(0, __float_as_int(x), C, 0xF, 0xF, true));
}
// sum + broadcast over an aligned 8-lane group (capsule dims)
__device__ __forceinline__ float red8(float x) {
  x = dppadd<0xB1>(x);   // quad_perm xor1
  x = dppadd<0x4E>(x);   // quad_perm xor2
  x = dppadd<0x141>(x);  // row_half_mirror crosses quads within 8 (quads uniform by now)
  return x;
}
// sum + broadcast across the 8 capsule groups (lane stride 8)
__device__ __forceinline__ float redk(float x) {
  x = dppadd<0x128>(x);  // xor8 via row_ror:8
  x = x + __int_as_float(__builtin_amdgcn_ds_swizzle(__float_as_int(x), 0x401F));  // xor16
  x = x + __shfl_xor(x, 32);                                                       // xor32
  return x;
}
// sum + broadcast over an aligned 16-lane group (mlp classes)
__device__ __forceinline__ float red16sum(float x) {
  x = dppadd<0xB1>(x);
  x = dppadd<0x4E>(x);
  x = x + __int_as_float(__builtin_amdgcn_ds_swizzle(__float_as_int(x), 0x101F));  // xor4
  x = x + __int_as_float(__builtin_amdgcn_ds_swizzle(__float_as_int(x), 0x201F));  // xor8
  return x;
}
__device__ __forceinline__ float red16max(float x) {
  x = fmaxf(x, dppmov<0xB1>(x));
  x = fmaxf(x, dppmov<0x4E>(x));
  x = fmaxf(x, __int_as_float(__builtin_amdgcn_ds_swizzle(__float_as_int(x), 0x101F)));
  x = fmaxf(x, __int_as_float(__builtin_amdgcn_ds_swizzle(__float_as_int(x), 0x201F)));
  return x;
}

// ---- reduce-scatter over an 8-lane group (routing distributed softmax) ----
__device__ __forceinline__ float rscatter8(const float p[8], int lane) {
  const bool j4 = (lane & 4) != 0, j2 = (lane & 2) != 0, j1 = (lane & 1) != 0;
  float k0 = j4 ? p[4] : p[0];
  float k1 = j4 ? p[5] : p[1];
  float k2 = j4 ? p[6] : p[2];
  float k3 = j4 ? p[7] : p[3];
  float s0 = j4 ? p[0] : p[4];
  float s1 = j4 ? p[1] : p[5];
  float s2 = j4 ? p[2] : p[6];
  float s3 = j4 ? p[3] : p[7];
  k0 += dppmov<0x141>(s0); k1 += dppmov<0x141>(s1);
  k2 += dppmov<0x141>(s2); k3 += dppmov<0x141>(s3);
  float t0 = j2 ? k2 : k0;
  float t1 = j2 ? k3 : k1;
  float u0 = j2 ? k0 : k2;
  float u1 = j2 ? k1 : k3;
  t0 += dppmov<0x4E>(u0); t1 += dppmov<0x4E>(u1);
  float a = j1 ? t1 : t0;
  float b = j1 ? t0 : t1;
  a += dppmov<0xB1>(b);
  return a;   // d for m = (lane&7)
}

// ---- allgather over an 8-lane group ----
__device__ __forceinline__ void agather8(float a, float w[8], int lane) {
  const bool j4 = (lane & 4) != 0, j2 = (lane & 2) != 0, j1 = (lane & 1) != 0;
  float pa = dppmov<0xB1>(a);
  float b0 = j1 ? pa : a;
  float b1 = j1 ? a : pa;
  float p0 = dppmov<0x4E>(b0), p1 = dppmov<0x4E>(b1);
  float q0 = j2 ? p0 : b0;
  float q1 = j2 ? p1 : b1;
  float q2 = j2 ? b0 : p0;
  float q3 = j2 ? b1 : p1;
  float m0 = dppmov<0x141>(q0), m1 = dppmov<0x141>(q1);
  float m2 = dppmov<0x141>(q2), m3 = dppmov<0x141>(q3);
  w[0] = j4 ? m0 : q0;  w[1] = j4 ? m1 : q1;
  w[2] = j4 ? m2 : q2;  w[3] = j4 ? m3 : q3;
  w[4] = j4 ? q0 : m0;  w[5] = j4 ? q1 : m1;
  w[6] = j4 ? q2 : m2;  w[7] = j4 ? q3 : m3;
}

// ---------------- wt_build: w [1024,256] -> FRAGMENT-LINEAR bf16 hi/lo ----------------
__global__ __launch_bounds__(256) void wt_build_kernel(
    const float* __restrict__ w, __bf16* __restrict__ wt_hi, __bf16* __restrict__ wt_lo) {
  const int gid  = blockIdx.x * 256 + threadIdx.x;  // 32768 = 32 kc x 16 g x 64 lanes
  const int lane = gid & 63;
  const int kc   = gid >> 10;
  const int g    = (gid >> 6) & 15;
  const int c = g * 16 + (lane & 15);
  const int k = kc * 32 + (lane >> 4) * 8;
  bf16x8 h, l;
#pragma unroll
  for (int j = 0; j < 8; ++j) {
    const float v = w[(size_t)(k + j) * DR + c];
    __bf16 hh, ll; splitbf(v, hh, ll);
    h[j] = hh; l[j] = ll;
  }
  *(bf16x8*)(wt_hi + (size_t)gid * 8) = h;
  *(bf16x8*)(wt_lo + (size_t)gid * 8) = l;
}

// ---------------- pad_zero ----------------
__global__ void pad_zero_kernel(float* __restrict__ p) {
  ((float4*)p)[threadIdx.x] = make_float4(0.f, 0.f, 0.f, 0.f);  // 64 threads x 16B
}

// ---------------- PCA via split-bf16 MFMA (round-14 form + conflict-free LDS) -------
// r15 lesson: launch_bounds(256,8) capped VGPR at 32 -> ILP destroyed (MfmaUtil 10%).
// Occupancy is NOT pca's lever; register-resident state is. Reverted to the r14 shape
// (128x64 tiles, VGPR 60, 3.75 blocks/CU, measured 103.7us). One change: LDS stride
// 40 -> 42 bf16 (84B = 21 banks, gcd(21,32)=1) to kill the 5.9M-cycle bank conflicts
// (~9% of kernel). XCD-sibling swizzle retained (FETCH 66MB).
__global__ __launch_bounds__(256, 4) void pca_mfma_kernel(
    const float* __restrict__ x, const __bf16* __restrict__ wt_hi,
    const __bf16* __restrict__ wt_lo, const float* __restrict__ b,
    float* __restrict__ out) {
  __shared__ __bf16 Ah[128][42];
  __shared__ __bf16 Al[128][42];
  const int t    = threadIdx.x;
  const int lane = t & 63;
  const int wv   = t >> 6;
  const int q    = lane >> 4;
  const int lm   = lane & 15;
  // swizzled decode: xcd = bid&7 preserved for all 4 col-group siblings of a row-block
  const int bid  = blockIdx.x;
  const int slot = bid >> 3;
  const int cg   = (slot & 3) << 2;                 // col-group base (16-col units)
  const int rblk = ((slot >> 2) << 3) + (bid & 7);  // row-block 0..239
  const int rowBase = rblk << 7;
  const int colBase = cg << 4;

  const int sr = t >> 2;
  const int sc = (t & 3) << 2;

  floatx4 acc[2][4];
#pragma unroll
  for (int rt = 0; rt < 2; ++rt)
#pragma unroll
    for (int ct = 0; ct < 4; ++ct)
      acc[rt][ct] = (floatx4){0.f, 0.f, 0.f, 0.f};

  const float* xrA = x + (size_t)(rowBase + sr) * NF + sc;
  const float* xrB = x + (size_t)(rowBase + sr + 64) * NF + sc;
  const bool okA = (rowBase + sr) < NN;
  const bool okB = (rowBase + sr + 64) < NN;

  const __bf16* wfh = wt_hi + ((size_t)cg << 9) + (lane << 3);
  const __bf16* wfl = wt_lo + ((size_t)cg << 9) + (lane << 3);

  float4 xv[4];
  xv[0] = okA ? *(const float4*)(xrA)      : make_float4(0.f, 0.f, 0.f, 0.f);
  xv[1] = okA ? *(const float4*)(xrA + 16) : make_float4(0.f, 0.f, 0.f, 0.f);
  xv[2] = okB ? *(const float4*)(xrB)      : make_float4(0.f, 0.f, 0.f, 0.f);
  xv[3] = okB ? *(const float4*)(xrB + 16) : make_float4(0.f, 0.f, 0.f, 0.f);

  for (int k0 = 0; k0 < NF; k0 += 32) {
    const int kc = k0 >> 5;
    bf16x8 bh[4], bl[4];
#pragma unroll
    for (int ct = 0; ct < 4; ++ct) {
      bh[ct] = *(const bf16x8*)(wfh + (((size_t)kc << 4) + ct) * 512);
      bl[ct] = *(const bf16x8*)(wfl + (((size_t)kc << 4) + ct) * 512);
    }
    asm volatile("s_waitcnt lgkmcnt(0)" ::: "memory");
    __builtin_amdgcn_s_barrier();
    {
#pragma unroll
      for (int i = 0; i < 4; ++i) {
        bf16x4 h4, l4;
        const float vs[4] = {xv[i].x, xv[i].y, xv[i].z, xv[i].w};
#pragma unroll
        for (int j = 0; j < 4; ++j) { __bf16 H, L; splitbf(vs[j], H, L); h4[j] = H; l4[j] = L; }
        const int row = sr + (i >> 1) * 64;
        const int col = sc + (i & 1) * 16;
        *(bf16x4*)&Ah[row][col] = h4;
        *(bf16x4*)&Al[row][col] = l4;
      }
    }
    float4 xn[4];
    if (k0 + 32 < NF) {
      xn[0] = okA ? *(const float4*)(xrA + k0 + 32) : make_float4(0.f, 0.f, 0.f, 0.f);
      xn[1] = okA ? *(const float4*)(xrA + k0 + 48) : make_float4(0.f, 0.f, 0.f, 0.f);
      xn[2] = okB ? *(const float4*)(xrB + k0 + 32) : make_float4(0.f, 0.f, 0.f, 0.f);
      xn[3] = okB ? *(const float4*)(xrB + k0 + 48) : make_float4(0.f, 0.f, 0.f, 0.f);
    } else {
#pragma unroll
      for (int i = 0; i < 4; ++i) xn[i] = make_float4(0.f, 0.f, 0.f, 0.f);
    }
    asm volatile("s_waitcnt lgkmcnt(0)" ::: "memory");
    __builtin_amdgcn_s_barrier();
#pragma unroll
    for (int rt = 0; rt < 2; ++rt) {
      const int ar = (wv << 5) + (rt << 4) + lm;
      const bf16x8 ah = *(const bf16x8*)&Ah[ar][q << 3];
      const bf16x8 al = *(const bf16x8*)&Al[ar][q << 3];
#pragma unroll
      for (int ct = 0; ct < 4; ++ct) {
        acc[rt][ct] = __builtin_amdgcn_mfma_f32_16x16x32_bf16(ah, bh[ct], acc[rt][ct], 0, 0, 0);
        acc[rt][ct] = __builtin_amdgcn_mfma_f32_16x16x32_bf16(ah, bl[ct], acc[rt][ct], 0, 0, 0);
        acc[rt][ct] = __builtin_amdgcn_mfma_f32_16x16x32_bf16(al, bh[ct], acc[rt][ct], 0, 0, 0);
      }
    }
#pragma unroll
    for (int i = 0; i < 4; ++i) xv[i] = xn[i];
  }
#pragma unroll
  for (int rt = 0; rt < 2; ++rt) {
#pragma unroll
    for (int ct = 0; ct < 4; ++ct) {
      const int col = colBase + (ct << 4) + lm;
      const float bias = b[col];
#pragma unroll
      for (int r = 0; r < 4; ++r) {
        const int row = rowBase + (wv << 5) + (rt << 4) + (q << 2) + r;
        if (row < NN) out[(size_t)row * DR + col] = fmaxf(acc[rt][ct][r] + bias, 0.f);
      }
    }
  }
}

// ---------- layer-0 normalize (k wave-uniform via blockIdx.y; round-8 form) ----------
__global__ __launch_bounds__(256, 4) void norm_fc_kernel(
    const float* __restrict__ hin, const float* __restrict__ fcw,
    const float* __restrict__ fcb, float* __restrict__ q) {
  const int k = blockIdx.y;
  const int n = blockIdx.x * 256 + threadIdx.x;
  if (n > NN) return;
  float* qrow = q + (size_t)n * DR + k * DDIM;
  if (n == NN) {
#pragma unroll
    for (int i = 0; i < DDIM; i += 4)
      *(float4*)(qrow + i) = make_float4(0.f, 0.f, 0.f, 0.f);
    return;
  }
  const float* hrow = hin + (size_t)n * DR + k * DDIM;
  float v[DDIM];
  float ss = 0.f;
#pragma unroll
  for (int i = 0; i < DDIM; i += 4) {
    float4 tv = *(const float4*)(hrow + i);
    tv.x = fmaxf(tv.x, 0.f); tv.y = fmaxf(tv.y, 0.f);
    tv.z = fmaxf(tv.z, 0.f); tv.w = fmaxf(tv.w, 0.f);
    v[i] = tv.x; v[i+1] = tv.y; v[i+2] = tv.z; v[i+3] = tv.w;
    ss += tv.x*tv.x + tv.y*tv.y + tv.z*tv.z + tv.w*tv.w;
  }
  float inv = 1.f / fmaxf(sqrtf(ss), 1e-12f);
#pragma unroll
  for (int i = 0; i < DDIM; ++i) v[i] *= inv;
#pragma unroll
  for (int i = 0; i < DDIM; ++i) asm volatile("" : "+v"(v[i]));
  float y[DDIM];
  ss = 0.f;
  const float* wk = fcw + (size_t)k * DDIM * DDIM;   // wave-uniform -> s_load
  const float* bk = fcb + k * DDIM;
#pragma unroll 4
  for (int o = 0; o < DDIM; ++o) {
    float a = bk[o];
#pragma unroll
    for (int i = 0; i < DDIM; i += 4) {
      const float4 wv = *(const float4*)(wk + o * DDIM + i);
      a += v[i]*wv.x + v[i+1]*wv.y + v[i+2]*wv.z + v[i+3]*wv.w;
    }
    a = fmaxf(a, 0.f);
    y[o] = a;
    ss += a * a;
  }
  inv = 1.f / fmaxf(sqrtf(ss), 1e-12f);
#pragma unroll
  for (int o = 0; o < DDIM; o += 4) {
    float4 tv;
    tv.x = y[o]*inv; tv.y = y[o+1]*inv; tv.z = y[o+2]*inv; tv.w = y[o+3]*inv;
    *(float4*)(qrow + o) = tv;
  }
}

// ---------------- routing: wave per node, DISTRIBUTED softmax (round-9 form) ----------------
__global__ __launch_bounds__(256, 4) void routing_kernel(
    const float* __restrict__ tab, const float* __restrict__ padrow,
    const int* __restrict__ nbr, const float* __restrict__ rawp,
    const int* __restrict__ ritp, float* __restrict__ uout, const int doNorm) {
  const int lane = threadIdx.x & 63;
  const int node = blockIdx.x * 4 + (threadIdx.x >> 6);
  const int off = (lane >> 3) * DDIM + (lane & 7) * 4;  // group (lane>>3) = capsule
  const float param = 1.f / (1.f + __expf(-rawp[0]));
  const float qparam = 1.f - param;
  const int iters = ritp[0];

  float4 z[MMN];
#pragma unroll
  for (int m = 0; m < MMN; ++m) {
    const int j = nbr[node * MMN + m];                    // wave-uniform
    const float* zrow = (j == NN) ? padrow : (tab + (size_t)j * DR);
    z[m] = *(const float4*)(zrow + off);
  }
  float4 ub = *(const float4*)(tab + (size_t)node * DR + off);

  // ---- iteration 0 (p == 0): uniform routing weights ----
  float4 S = make_float4(0.f, 0.f, 0.f, 0.f);
#pragma unroll
  for (int m = 0; m < MMN; ++m) {
    S.x += z[m].x; S.y += z[m].y; S.z += z[m].z; S.w += z[m].w;
  }
  const float w0 = param * 0.0625f + qparam * 0.125f;  // param/16 + (1-param)/8
  ub.x += w0 * S.x; ub.y += w0 * S.y; ub.z += w0 * S.z; ub.w += w0 * S.w;

  float4 u = ub;
  if (iters > 1) {
    float ss = red8(ub.x*ub.x + ub.y*ub.y + ub.z*ub.z + ub.w*ub.w);
    const float inv = 1.f / fmaxf(sqrtf(ss), 1e-12f);
    u.x = ub.x*inv; u.y = ub.y*inv; u.z = ub.z*inv; u.w = ub.w*inv;
  }

  for (int it = 1; it < iters; ++it) {
    float pA[8], pB[8];
#pragma unroll
    for (int m = 0; m < 8; ++m) {
      pA[m] = z[m].x*u.x + z[m].y*u.y + z[m].z*u.z + z[m].w*u.w;
      pB[m] = z[m+8].x*u.x + z[m+8].y*u.y + z[m+8].z*u.z + z[m+8].w*u.w;
    }
    const float dA = rscatter8(pA, lane);
    const float dB = rscatter8(pB, lane);
    const float eA = __expf(dA);
    const float eB = __expf(dB);
    const float smk = red8(eA + eB);
    const float skA = redk(eA);
    const float skB = redk(eB);
    const float c1 = param * __builtin_amdgcn_rcpf(smk);
    const float wA = eA * (c1 + qparam * __builtin_amdgcn_rcpf(skA));
    const float wB = eB * (c1 + qparam * __builtin_amdgcn_rcpf(skB));
    float wS[8], wT[8];
    agather8(wA, wS, lane);
    agather8(wB, wT, lane);
    float4 un = ub;
#pragma unroll
    for (int m = 0; m < 8; ++m) {
      un.x += wS[m]*z[m].x;   un.y += wS[m]*z[m].y;
      un.z += wS[m]*z[m].z;   un.w += wS[m]*z[m].w;
      un.x += wT[m]*z[m+8].x; un.y += wT[m]*z[m+8].y;
      un.z += wT[m]*z[m+8].z; un.w += wT[m]*z[m+8].w;
    }
    ub = un;
    if (it < iters - 1) {
      float ss = red8(un.x*un.x + un.y*un.y + un.z*un.z + un.w*un.w);
      const float inv = 1.f / fmaxf(sqrtf(ss), 1e-12f);
      u.x = un.x*inv; u.y = un.y*inv; u.z = un.z*inv; u.w = un.w*inv;
    }
  }
  float4 w = ub;
  if (doNorm) {
    w.x = fmaxf(w.x, 0.f); w.y = fmaxf(w.y, 0.f);
    w.z = fmaxf(w.z, 0.f); w.w = fmaxf(w.w, 0.f);
    float ss = red8(w.x*w.x + w.y*w.y + w.z*w.z + w.w*w.w);
    const float inv = 1.f / fmaxf(sqrtf(ss), 1e-12f);
    w.x *= inv; w.y *= inv; w.z *= inv; w.w *= inv;
  }
  *(float4*)(uout + (size_t)node * DR + off) = w;
}

// ---------------- MLP head via split-bf16 MFMA + log_softmax (round-10 form) ----------------
__global__ __launch_bounds__(256) void mlp_kernel(
    const float* __restrict__ h, const float* __restrict__ w,
    const float* __restrict__ b, float* __restrict__ out) {
  const int lane = threadIdx.x & 63;
  const int wv   = threadIdx.x >> 6;
  const int q    = lane >> 4;
  const int lm   = lane & 15;
  const int nodeTile = blockIdx.x * 64 + wv * 16;
  const int nodeA = nodeTile + lm;            // A-operand row owned by this lane
  const bool okA = nodeA < NN;
  const float* hp = h + (size_t)nodeA * DR + (q << 3);
  const float* wp = w + (size_t)lm * DR + (q << 3);

  floatx4 acc = (floatx4){0.f, 0.f, 0.f, 0.f};
#pragma unroll
  for (int kc = 0; kc < 8; ++kc) {
    bf16x8 ah, al, bh, bl;
    {
      float va[8];
      if (okA) {
        *(float4*)&va[0] = *(const float4*)(hp + kc * 32);
        *(float4*)&va[4] = *(const float4*)(hp + kc * 32 + 4);
      } else {
#pragma unroll
        for (int j = 0; j < 8; ++j) va[j] = 0.f;
      }
#pragma unroll
      for (int j = 0; j < 8; ++j) { __bf16 H, L; splitbf(va[j], H, L); ah[j] = H; al[j] = L; }
    }
    {
      float vb[8];
      *(float4*)&vb[0] = *(const float4*)(wp + kc * 32);
      *(float4*)&vb[4] = *(const float4*)(wp + kc * 32 + 4);
#pragma unroll
      for (int j = 0; j < 8; ++j) { __bf16 H, L; splitbf(vb[j], H, L); bh[j] = H; bl[j] = L; }
    }
    acc = __builtin_amdgcn_mfma_f32_16x16x32_bf16(ah, bh, acc, 0, 0, 0);
    acc = __builtin_amdgcn_mfma_f32_16x16x32_bf16(ah, bl, acc, 0, 0, 0);
    acc = __builtin_amdgcn_mfma_f32_16x16x32_bf16(al, bh, acc, 0, 0, 0);
  }
  const float bias = b[lm];
#pragma unroll
  for (int r = 0; r < 4; ++r) {
    const int nrow = nodeTile + (q << 2) + r;
    const float lg = acc[r] + bias;
    const float mx = red16max(lg);
    const float e  = __expf(lg - mx);
    const float se = red16sum(e);
    const float lp = lg - mx - __logf(se);
    if (nrow < NN) out[(size_t)nrow * NC + lm] = lp;
  }
}

extern "C" void kernel_launch(void* const* d_in, const int* in_sizes, int n_in,
                              void* d_out, int out_size, void* d_ws, size_t ws_size,
                              hipStream_t stream) {
  const float* x     = (const float*)d_in[0];
  const int*   nbr   = (const int*)  d_in[1];
  const float* pca_w = (const float*)d_in[2];
  const float* pca_b = (const float*)d_in[3];
  const float* rawp  = (const float*)d_in[4];
  const float* fc_w  = (const float*)d_in[5];
  const float* fc_b  = (const float*)d_in[6];
  const float* mlp_w = (const float*)d_in[7];
  const float* mlp_b = (const float*)d_in[8];
  const int*   ritp  = (const int*)  d_in[9];

  float* out  = (float*)d_out;                  // log_probs [NN,NC] then h [NN,DR]
  float* EMB  = out + (size_t)NN * NC;          // embedding region; also ping table B rows
  float* Bpad = EMB - DR;                       // table-B zero row (dead until mlp)
  float* Q    = (float*)d_ws;                   // [NN+1, DR] table A (+pad row NN)
  float* Qpad = Q + (size_t)NN * DR;

  // wt scratch: first 1MB of log_probs region (disjoint from Bpad; dead until mlp)
  __bf16* wt_hi = (__bf16*)d_out;               // fragment-linear [32][16][64][8]
  __bf16* wt_lo = wt_hi + (size_t)DR * NF;

  wt_build_kernel<<<128, 256, 0, stream>>>(pca_w, wt_hi, wt_lo);
  pad_zero_kernel<<<1, 64, 0, stream>>>(Bpad);
  // PCA + relu -> raw h rows at EMB (128x64 tiles, XCD-sibling swizzle, 960 blocks)
  pca_mfma_kernel<<<960, 256, 0, stream>>>(x, wt_hi, wt_lo, pca_b, EMB);
  // layer 0 prep (per-capsule fc) -> Q ; k wave-uniform via blockIdx.y
  norm_fc_kernel<<<dim3((NN + 1 + 255) / 256, KC), 256, 0, stream>>>(EMB, fc_w, fc_b, Q);
  // L0: Q -> B (normalized epilogue)
  routing_kernel<<<NN / 4, 256, 0, stream>>>(Q, Qpad, nbr, rawp, ritp, EMB, 1);
  // L1: B -> Q (normalized epilogue)
  routing_kernel<<<NN / 4, 256, 0, stream>>>(EMB, Bpad, nbr, rawp, ritp, Q, 1);
  // L2: Q -> EMB raw (final embedding)
  routing_kernel<<<NN / 4, 256, 0, stream>>>(Q, Qpad, nbr, rawp, ritp, EMB, 0);
  // classifier head (16-node x 16-class MFMA tiles)
  mlp_kernel<<<(NN + 63) / 64, 256, 0, stream>>>(EMB, mlp_w, mlp_b, out);
}